// Round 1
// baseline (5278.682 us; speedup 1.0000x reference)
//
#include <hip/hip_runtime.h>
#include <hip/hip_bf16.h>

#define QLEN 1024
#define KLEN 2560
#define MTOT 1536   // KLEN - QLEN
#define BSZ 2
#define NH 16
#define DH 64
#define DMODEL 1024
#define DINNER 4096

// ---------------------------------------------------------------------------
// Generic tiled f32 GEMM: C(MxN) = A(MxK) @ B(KxN), row-major.
// EPI: 0 = none, 1 = bias+relu, 2 = bias
// GATHER: A rows gathered from [g0 (g0rows) | g1 (g1rows) | A] (the concat).
// Requires M%64==0, N%64==0, K%16==0 (true for all shapes here).
// ---------------------------------------------------------------------------
template <int EPI, bool GATHER>
__global__ __launch_bounds__(256) void gemm_f32(
    const float* __restrict__ A, const float* __restrict__ B,
    const float* __restrict__ bias, float* __restrict__ C,
    int M, int N, int K,
    const float* __restrict__ g0, int g0rows,
    const float* __restrict__ g1, int g1rows)
{
    __shared__ float As[16][68];   // [k][m], padded stride 68 (16B-aligned rows)
    __shared__ float Bs[16][64];   // [k][n]

    const int tid = threadIdx.x;
    const int tx = tid & 15;       // output col group
    const int ty = tid >> 4;       // output row group
    const int bm = blockIdx.y * 64;
    const int bn = blockIdx.x * 64;

    // A-tile load mapping: thread -> (row, 4-wide k group)
    const int ar  = tid >> 2;        // 0..63
    const int akg = (tid & 3) * 4;   // 0,4,8,12
    // B-tile load mapping
    const int br = tid >> 4;         // 0..15
    const int bc = (tid & 15) * 4;   // 0..60

    const float* arow;
    {
        int m = bm + ar;
        if (GATHER) {
            if (m < g0rows)               arow = g0 + (size_t)m * K;
            else if (m < g0rows + g1rows) arow = g1 + (size_t)(m - g0rows) * K;
            else                          arow = A  + (size_t)(m - g0rows - g1rows) * K;
        } else {
            arow = A + (size_t)m * K;
        }
    }

    float acc[4][4] = {};

    for (int k0 = 0; k0 < K; k0 += 16) {
        const float4 a4 = *(const float4*)(arow + k0 + akg);
        const float4 b4 = *(const float4*)(B + (size_t)(k0 + br) * N + bn + bc);
        __syncthreads();   // previous tile fully consumed
        As[akg + 0][ar] = a4.x;
        As[akg + 1][ar] = a4.y;
        As[akg + 2][ar] = a4.z;
        As[akg + 3][ar] = a4.w;
        *(float4*)&Bs[br][bc] = b4;
        __syncthreads();
        #pragma unroll
        for (int kk = 0; kk < 16; kk++) {
            const float4 av4 = *(const float4*)&As[kk][ty * 4];
            const float4 bv4 = *(const float4*)&Bs[kk][tx * 4];
            const float a_[4] = {av4.x, av4.y, av4.z, av4.w};
            const float b_[4] = {bv4.x, bv4.y, bv4.z, bv4.w};
            #pragma unroll
            for (int ii = 0; ii < 4; ii++)
                #pragma unroll
                for (int jj = 0; jj < 4; jj++)
                    acc[ii][jj] += a_[ii] * b_[jj];
        }
    }

    #pragma unroll
    for (int ii = 0; ii < 4; ii++) {
        const int row = bm + ty * 4 + ii;
        const int col = bn + tx * 4;
        float vv[4];
        #pragma unroll
        for (int jj = 0; jj < 4; jj++) {
            float v = acc[ii][jj];
            if (EPI >= 1) v += bias[col + jj];
            if (EPI == 1) v = fmaxf(v, 0.0f);
            vv[jj] = v;
        }
        *(float4*)(C + (size_t)row * N + col) = make_float4(vv[0], vv[1], vv[2], vv[3]);
    }
}

// ---------------------------------------------------------------------------
// Fused rel-pos attention, flash-style online softmax.
// Block: 64 threads = 64 query rows for one (b, n). Grid: (QLEN/64, BSZ*NH).
// score(i,j) = 0.125 * ( q_i·(k_j + r_m) + rwb·k_j + rrb·r_m ),  m = j+1023-i
// masked (skipped) when j > i + MTOT.
// ---------------------------------------------------------------------------
__global__ __launch_bounds__(64) void attn_kernel(
    const float* __restrict__ wh,   // (KLEN, BSZ, 3072)
    const float* __restrict__ rk,   // (KLEN, NH, DH)
    const float* __restrict__ rwb,  // (NH, DH)
    const float* __restrict__ rrb,  // (NH, DH)
    float* __restrict__ av)         // (QLEN, BSZ, NH*DH)
{
    const int i0  = blockIdx.x * 64;
    const int b   = blockIdx.y >> 4;
    const int n   = blockIdx.y & 15;
    const int tid = threadIdx.x;
    const int i   = i0 + tid;

    __shared__ float qs[64][65];
    __shared__ float ks[32][64];
    __shared__ float vs[32][64];
    __shared__ float rs[96][65];
    __shared__ float ck[32];
    __shared__ float cr[96];
    __shared__ float rwbs[64], rrbs[64];

    rwbs[tid] = rwb[n * 64 + tid];
    rrbs[tid] = rrb[n * 64 + tid];

    // load 64 q rows, coalesced (thread = d index)
    for (int r = 0; r < 64; r++)
        qs[r][tid] = wh[((size_t)(MTOT + i0 + r) * BSZ + b) * 3072 + n * 64 + tid];

    float acc[64];
    #pragma unroll
    for (int d = 0; d < 64; d++) acc[d] = 0.0f;
    float mrun = -3.0e38f, l = 0.0f;

    const int jend = min(KLEN, i0 + 63 + MTOT + 1);  // multiple of 32
    for (int j0 = 0; j0 < jend; j0 += 32) {
        __syncthreads();
        for (int r = 0; r < 32; r++) {
            ks[r][tid] = wh[((size_t)(j0 + r) * BSZ + b) * 3072 + 1024 + n * 64 + tid];
            vs[r][tid] = wh[((size_t)(j0 + r) * BSZ + b) * 3072 + 2048 + n * 64 + tid];
        }
        const int m0 = j0 - i0 + 960;
        for (int r = 0; r < 95; r++) {
            const int m = m0 + r;
            rs[r][tid] = (m < KLEN) ? rk[((size_t)m * NH + n) * 64 + tid] : 0.0f;
        }
        __syncthreads();
        // per-tile bias dot-products (shared across queries)
        if (tid < 32) {
            float s = 0.0f;
            #pragma unroll
            for (int d = 0; d < 64; d++) s += rwbs[d] * ks[tid][d];
            ck[tid] = s;
        }
        {
            float s = 0.0f;
            #pragma unroll
            for (int d = 0; d < 64; d++) s += rrbs[d] * rs[tid][d];
            cr[tid] = s;
            if (tid < 31) {
                float s2 = 0.0f;
                #pragma unroll
                for (int d = 0; d < 64; d++) s2 += rrbs[d] * rs[tid + 64][d];
                cr[tid + 64] = s2;
            }
        }
        __syncthreads();

        for (int jj = 0; jj < 32; jj++) {
            const int j = j0 + jj;
            if (j > i + MTOT) break;          // masked: this and all later jj
            const int mrow = jj + 63 - tid;   // in [0, 94]
            float s = 0.0f;
            #pragma unroll
            for (int d = 0; d < 64; d++)
                s += qs[tid][d] * (ks[jj][d] + rs[mrow][d]);
            s = (s + ck[jj] + cr[mrow]) * 0.125f;

            if (s > mrun) {
                const float corr = __expf(mrun - s);
                mrun = s;
                l = l * corr + 1.0f;
                #pragma unroll
                for (int d = 0; d < 64; d++) acc[d] = acc[d] * corr + vs[jj][d];
            } else {
                const float p = __expf(s - mrun);
                l += p;
                #pragma unroll
                for (int d = 0; d < 64; d++) acc[d] += p * vs[jj][d];
            }
        }
    }

    const float inv = 1.0f / l;
    #pragma unroll
    for (int d = 0; d < 64; d++)
        av[((size_t)i * BSZ + b) * 1024 + n * 64 + d] = acc[d] * inv;
}

// ---------------------------------------------------------------------------
// LayerNorm with residual add: out = LN(x + res) * scale + bias, D=1024.
// One 256-thread block per row, 4 elements/thread.
// ---------------------------------------------------------------------------
__global__ __launch_bounds__(256) void ln_kernel(
    const float* __restrict__ x, const float* __restrict__ res,
    const float* __restrict__ scale, const float* __restrict__ bias,
    float* __restrict__ out)
{
    const int row = blockIdx.x;
    const int tid = threadIdx.x;
    const size_t base = (size_t)row * 1024 + tid * 4;
    const float4 xv = *(const float4*)(x + base);
    const float4 rv = *(const float4*)(res + base);
    float v[4] = {xv.x + rv.x, xv.y + rv.y, xv.z + rv.z, xv.w + rv.w};
    float s  = v[0] + v[1] + v[2] + v[3];
    float ss = v[0]*v[0] + v[1]*v[1] + v[2]*v[2] + v[3]*v[3];
    #pragma unroll
    for (int off = 32; off >= 1; off >>= 1) {
        s  += __shfl_down(s, off);
        ss += __shfl_down(ss, off);
    }
    __shared__ float red[8];
    const int lane = tid & 63, wid = tid >> 6;
    if (lane == 0) { red[wid] = s; red[4 + wid] = ss; }
    __syncthreads();
    if (tid == 0) {
        red[0] = red[0] + red[1] + red[2] + red[3];
        red[4] = red[4] + red[5] + red[6] + red[7];
    }
    __syncthreads();
    const float mean = red[0] * (1.0f / 1024.0f);
    const float var  = red[4] * (1.0f / 1024.0f) - mean * mean;
    const float rstd = rsqrtf(var + 1e-5f);
    const float4 sc = *(const float4*)(scale + tid * 4);
    const float4 bi = *(const float4*)(bias + tid * 4);
    float4 o;
    o.x = (v[0] - mean) * rstd * sc.x + bi.x;
    o.y = (v[1] - mean) * rstd * sc.y + bi.y;
    o.z = (v[2] - mean) * rstd * sc.z + bi.z;
    o.w = (v[3] - mean) * rstd * sc.w + bi.w;
    *(float4*)(out + base) = o;
}

// ---------------------------------------------------------------------------
extern "C" void kernel_launch(void* const* d_in, const int* in_sizes, int n_in,
                              void* d_out, int out_size, void* d_ws, size_t ws_size,
                              hipStream_t stream) {
    const float* input_ids = (const float*)d_in[0];
    const float* pos_emb   = (const float*)d_in[1];
    const float* mem       = (const float*)d_in[2];
    const float* c_mem     = (const float*)d_in[3];
    // d_in[4] attn_mask: recomputed analytically (j > i + MTOT)
    const float* qkv_w     = (const float*)d_in[5];
    const float* r_w       = (const float*)d_in[6];
    const float* o_w       = (const float*)d_in[7];
    const float* r_w_bias  = (const float*)d_in[8];
    const float* r_r_bias  = (const float*)d_in[9];
    const float* ln_a_s    = (const float*)d_in[10];
    const float* ln_a_b    = (const float*)d_in[11];
    const float* ff_w1     = (const float*)d_in[12];
    const float* ff_b1     = (const float*)d_in[13];
    const float* ff_w2     = (const float*)d_in[14];
    const float* ff_b2     = (const float*)d_in[15];
    const float* ln_f_s    = (const float*)d_in[16];
    const float* ln_f_b    = (const float*)d_in[17];

    float* ws = (float*)d_ws;
    // layout (floats); peak use = 20,447,232 floats = 81.8 MB
    float* wh   = ws;                    // 15,728,640 : (KLEN*BSZ, 3072)
    float* rk   = ws + 15728640;         //  2,621,440 : (KLEN, NH*DH)
    float* av   = ws + 18350080;         //  2,097,152 : attn_vec
    float* ao   = ws + 0;                //  2,097,152 : attn_out   (reuses wh)
    float* ares = ws + 2097152;          //  2,097,152 : attn_res   (reuses wh)
    float* h1   = ws + 4194304;          //  8,388,608 : ff hidden  (reuses wh)
    float* h2   = ws + 12582912;         //  2,097,152 : ff out     (reuses wh)

    const dim3 thr(256);

    // 1) w_heads = [mem|c_mem|input] @ qkv_w   (5120 x 3072 x 1024)
    gemm_f32<0, true><<<dim3(48, 80), thr, 0, stream>>>(
        input_ids, qkv_w, nullptr, wh, 5120, 3072, 1024, mem, 2048, c_mem, 1024);
    // 2) r_k = pos_emb @ r_w                   (2560 x 1024 x 1024)
    gemm_f32<0, false><<<dim3(16, 40), thr, 0, stream>>>(
        pos_emb, r_w, nullptr, rk, 2560, 1024, 1024, nullptr, 0, nullptr, 0);
    // 3) fused attention -> attn_vec
    attn_kernel<<<dim3(16, 32), dim3(64), 0, stream>>>(wh, rk, r_w_bias, r_r_bias, av);
    // 4) attn_out = attn_vec @ o_w             (2048 x 1024 x 1024)
    gemm_f32<0, false><<<dim3(16, 32), thr, 0, stream>>>(
        av, o_w, nullptr, ao, 2048, 1024, 1024, nullptr, 0, nullptr, 0);
    // 5) attn_res = LN(input + attn_out)
    ln_kernel<<<dim3(2048), thr, 0, stream>>>(ao, input_ids, ln_a_s, ln_a_b, ares);
    // 6) h1 = relu(attn_res @ ff_w1 + b1)      (2048 x 4096 x 1024)
    gemm_f32<1, false><<<dim3(64, 32), thr, 0, stream>>>(
        ares, ff_w1, ff_b1, h1, 2048, 4096, 1024, nullptr, 0, nullptr, 0);
    // 7) h2 = h1 @ ff_w2 + b2                  (2048 x 1024 x 4096)
    gemm_f32<2, false><<<dim3(16, 32), thr, 0, stream>>>(
        h1, ff_w2, ff_b2, h2, 2048, 1024, 4096, nullptr, 0, nullptr, 0);
    // 8) out = LN(attn_res + h2)
    ln_kernel<<<dim3(2048), thr, 0, stream>>>(h2, ares, ln_f_s, ln_f_b, (float*)d_out);
}

// Round 2
// 1233.883 us; speedup vs baseline: 4.2781x; 4.2781x over previous
//
#include <hip/hip_runtime.h>
#include <hip/hip_bf16.h>

#define QLEN 1024
#define KLEN 2560
#define MTOT 1536   // KLEN - QLEN
#define BSZ 2
#define NH 16
#define DH 64
#define DMODEL 1024
#define DINNER 4096

typedef short bf16x8 __attribute__((ext_vector_type(8)));
typedef float f32x4  __attribute__((ext_vector_type(4)));

__device__ __forceinline__ short f2bf(float f) {
    union { float f; unsigned u; } v; v.f = f;
    unsigned r = v.u + 0x7FFFu + ((v.u >> 16) & 1u);
    return (short)(r >> 16);
}

// ---------------------------------------------------------------------------
// Generic tiled f32 GEMM (unchanged from round 1): C = A @ B, row-major.
// ---------------------------------------------------------------------------
template <int EPI, bool GATHER>
__global__ __launch_bounds__(256) void gemm_f32(
    const float* __restrict__ A, const float* __restrict__ B,
    const float* __restrict__ bias, float* __restrict__ C,
    int M, int N, int K,
    const float* __restrict__ g0, int g0rows,
    const float* __restrict__ g1, int g1rows)
{
    __shared__ float As[16][68];
    __shared__ float Bs[16][64];

    const int tid = threadIdx.x;
    const int tx = tid & 15;
    const int ty = tid >> 4;
    const int bm = blockIdx.y * 64;
    const int bn = blockIdx.x * 64;

    const int ar  = tid >> 2;
    const int akg = (tid & 3) * 4;
    const int br = tid >> 4;
    const int bc = (tid & 15) * 4;

    const float* arow;
    {
        int m = bm + ar;
        if (GATHER) {
            if (m < g0rows)               arow = g0 + (size_t)m * K;
            else if (m < g0rows + g1rows) arow = g1 + (size_t)(m - g0rows) * K;
            else                          arow = A  + (size_t)(m - g0rows - g1rows) * K;
        } else {
            arow = A + (size_t)m * K;
        }
    }

    float acc[4][4] = {};

    for (int k0 = 0; k0 < K; k0 += 16) {
        const float4 a4 = *(const float4*)(arow + k0 + akg);
        const float4 b4 = *(const float4*)(B + (size_t)(k0 + br) * N + bn + bc);
        __syncthreads();
        As[akg + 0][ar] = a4.x;
        As[akg + 1][ar] = a4.y;
        As[akg + 2][ar] = a4.z;
        As[akg + 3][ar] = a4.w;
        *(float4*)&Bs[br][bc] = b4;
        __syncthreads();
        #pragma unroll
        for (int kk = 0; kk < 16; kk++) {
            const float4 av4 = *(const float4*)&As[kk][ty * 4];
            const float4 bv4 = *(const float4*)&Bs[kk][tx * 4];
            const float a_[4] = {av4.x, av4.y, av4.z, av4.w};
            const float b_[4] = {bv4.x, bv4.y, bv4.z, bv4.w};
            #pragma unroll
            for (int ii = 0; ii < 4; ii++)
                #pragma unroll
                for (int jj = 0; jj < 4; jj++)
                    acc[ii][jj] += a_[ii] * b_[jj];
        }
    }

    #pragma unroll
    for (int ii = 0; ii < 4; ii++) {
        const int row = bm + ty * 4 + ii;
        const int col = bn + tx * 4;
        float vv[4];
        #pragma unroll
        for (int jj = 0; jj < 4; jj++) {
            float v = acc[ii][jj];
            if (EPI >= 1) v += bias[col + jj];
            if (EPI == 1) v = fmaxf(v, 0.0f);
            vv[jj] = v;
        }
        *(float4*)(C + (size_t)row * N + col) = make_float4(vv[0], vv[1], vv[2], vv[3]);
    }
}

// ---------------------------------------------------------------------------
// MFMA flash attention with fused rel-shift.
// Block: 256 threads = 4 waves; wave w owns 16 query rows (i_base = i0+16w).
// Grid: (QLEN/64, BSZ*NH).
// score(i,j) = 0.125*( (q_i+rwb)·k_j + (q_i+rrb)·r_m ),  m = j+1023-i,
// masked when j > i + MTOT.
// mfma_f32_16x16x32_bf16 layouts (guide §3, m89-verified):
//   A: row = l&15, k = (l>>4)*8+e ; B: col = l&15, k = (l>>4)*8+e
//   D: col = l&15, row = (l>>4)*4+reg
// ---------------------------------------------------------------------------
__global__ __launch_bounds__(256) void attn_mfma(
    const float* __restrict__ wh,   // (KLEN, BSZ, 3072)
    const float* __restrict__ rk,   // (KLEN, NH, DH)
    const float* __restrict__ rwb,  // (NH, DH)
    const float* __restrict__ rrb,  // (NH, DH)
    float* __restrict__ av)         // (QLEN, BSZ, NH*DH)
{
    __shared__ __align__(16) short Ks[64][72];      // K  [key][d]
    __shared__ __align__(16) short Vs[64][72];      // V^T [d][key]
    __shared__ __align__(16) short Rs[128][72];     // R  [m-Mlo][d]
    __shared__ __align__(16) short Ps[4][16][72];   // per-wave P [q][key]

    const int i0  = blockIdx.x * 64;
    const int b   = blockIdx.y >> 4;
    const int n   = blockIdx.y & 15;
    const int tid = threadIdx.x;
    const int w   = tid >> 6;
    const int l   = tid & 63;
    const int lg  = l >> 4;     // 16-lane group 0..3
    const int lc  = l & 15;
    const int i_base = i0 + 16 * w;

    // ---- Q fragments (held in registers for the whole kernel) ----
    bf16x8 aqw[2], aqr[2];
    {
        const int i = i_base + lc;
        const float* qp = wh + ((size_t)(MTOT + i) * BSZ + b) * 3072 + n * 64;
        #pragma unroll
        for (int kc = 0; kc < 2; kc++) {
            const int d0 = kc * 32 + lg * 8;
            #pragma unroll
            for (int e = 0; e < 8; e++) {
                const float qv = qp[d0 + e];
                aqw[kc][e] = f2bf(qv + rwb[n * 64 + d0 + e]);
                aqr[kc][e] = f2bf(qv + rrb[n * 64 + d0 + e]);
            }
        }
    }

    f32x4 o_acc[4];
    #pragma unroll
    for (int nt = 0; nt < 4; nt++) o_acc[nt] = (f32x4){0.f, 0.f, 0.f, 0.f};
    float mrun[4] = {-1e30f, -1e30f, -1e30f, -1e30f};
    float lrun[4] = {0.f, 0.f, 0.f, 0.f};

    const int jend = i0 + 1600;           // last unmasked j for this block +1
    for (int j0 = 0; j0 < jend; j0 += 64) {
        __syncthreads();
        // ---- stage K (natural) and V (transposed) ----
        {
            const int row = tid >> 2;
            const int c0  = (tid & 3) * 16;
            const float* kp = wh + ((size_t)(j0 + row) * BSZ + b) * 3072 + 1024 + n * 64 + c0;
            const float* vp = kp + 1024;
            #pragma unroll
            for (int u = 0; u < 4; u++) {
                const float4 kv = *(const float4*)(kp + 4 * u);
                unsigned p0 = (unsigned)(unsigned short)f2bf(kv.x) |
                              ((unsigned)(unsigned short)f2bf(kv.y) << 16);
                unsigned p1 = (unsigned)(unsigned short)f2bf(kv.z) |
                              ((unsigned)(unsigned short)f2bf(kv.w) << 16);
                *(unsigned*)&Ks[row][c0 + 4 * u]     = p0;
                *(unsigned*)&Ks[row][c0 + 4 * u + 2] = p1;
                const float4 vv = *(const float4*)(vp + 4 * u);
                Vs[c0 + 4 * u + 0][row] = f2bf(vv.x);
                Vs[c0 + 4 * u + 1][row] = f2bf(vv.y);
                Vs[c0 + 4 * u + 2][row] = f2bf(vv.z);
                Vs[c0 + 4 * u + 3][row] = f2bf(vv.w);
            }
        }
        // ---- stage R (128 rows, window Mlo = j0-i0+960) ----
        {
            const int row = tid >> 1;
            const int c0  = (tid & 1) * 32;
            const int m   = j0 - i0 + 960 + row;
            if (m < KLEN) {
                const float* rp = rk + ((size_t)m * NH + n) * 64 + c0;
                #pragma unroll
                for (int u = 0; u < 8; u++) {
                    const float4 rv = *(const float4*)(rp + 4 * u);
                    unsigned p0 = (unsigned)(unsigned short)f2bf(rv.x) |
                                  ((unsigned)(unsigned short)f2bf(rv.y) << 16);
                    unsigned p1 = (unsigned)(unsigned short)f2bf(rv.z) |
                                  ((unsigned)(unsigned short)f2bf(rv.w) << 16);
                    *(unsigned*)&Rs[row][c0 + 4 * u]     = p0;
                    *(unsigned*)&Rs[row][c0 + 4 * u + 2] = p1;
                }
            } else {
                #pragma unroll
                for (int u = 0; u < 16; u++)
                    *(unsigned*)&Rs[row][c0 + 2 * u] = 0u;
            }
        }
        __syncthreads();

        // ---- AC = (Q+rwb) @ K^T : 4 col-tiles of 16 keys ----
        f32x4 sfr[4];
        #pragma unroll
        for (int jt = 0; jt < 4; jt++) {
            const bf16x8 bk0 = *(const bf16x8*)&Ks[16 * jt + lc][lg * 8];
            const bf16x8 bk1 = *(const bf16x8*)&Ks[16 * jt + lc][32 + lg * 8];
            f32x4 acc = (f32x4){0.f, 0.f, 0.f, 0.f};
            acc = __builtin_amdgcn_mfma_f32_16x16x32_bf16(aqw[0], bk0, acc, 0, 0, 0);
            acc = __builtin_amdgcn_mfma_f32_16x16x32_bf16(aqw[1], bk1, acc, 0, 0, 0);
            sfr[jt] = acc;
        }
        // ---- Dr = (Q+rrb) @ R^T : 5 col-tiles (80 shift positions) ----
        f32x4 dr[5];
        #pragma unroll
        for (int mt = 0; mt < 5; mt++) {
            const int rrow = 16 * mt + lc + 48 - 16 * w;
            const bf16x8 br0 = *(const bf16x8*)&Rs[rrow][lg * 8];
            const bf16x8 br1 = *(const bf16x8*)&Rs[rrow][32 + lg * 8];
            f32x4 acc = (f32x4){0.f, 0.f, 0.f, 0.f};
            acc = __builtin_amdgcn_mfma_f32_16x16x32_bf16(aqr[0], br0, acc, 0, 0, 0);
            acc = __builtin_amdgcn_mfma_f32_16x16x32_bf16(aqr[1], br1, acc, 0, 0, 0);
            dr[mt] = acc;
        }

        // ---- combine (rel-shift gather) + online softmax ----
        #pragma unroll
        for (int r = 0; r < 4; r++) {
            const int q   = 4 * lg + r;            // row within wave tile
            const int o   = lc + 15 - q;           // Dr col offset (0..30)
            const int src = (l & 48) | (o & 15);   // source lane in row-group
            float sv[4];
            float mx = -1e30f;
            #pragma unroll
            for (int jt = 0; jt < 4; jt++) {
                const float v0 = __shfl(dr[jt][r], src);
                const float v1 = __shfl(dr[jt + 1][r], src);
                const float bd = (o < 16) ? v0 : v1;
                float s = (sfr[jt][r] + bd) * 0.125f;
                const int j = j0 + 16 * jt + lc;
                if (j > i_base + q + MTOT) s = -1e30f;
                sv[jt] = s;
                mx = fmaxf(mx, s);
            }
            #pragma unroll
            for (int msk = 1; msk <= 8; msk <<= 1)
                mx = fmaxf(mx, __shfl_xor(mx, msk));
            const float mnew = fmaxf(mrun[r], mx);
            const float corr = __expf(mrun[r] - mnew);
            mrun[r] = mnew;
            float ps = 0.f;
            #pragma unroll
            for (int jt = 0; jt < 4; jt++) {
                const float p = __expf(sv[jt] - mnew);
                ps += p;
                Ps[w][q][16 * jt + lc] = f2bf(p);
            }
            #pragma unroll
            for (int msk = 1; msk <= 8; msk <<= 1)
                ps += __shfl_xor(ps, msk);
            lrun[r] = lrun[r] * corr + ps;
            #pragma unroll
            for (int nt = 0; nt < 4; nt++) o_acc[nt][r] *= corr;
        }

        // wave-local: ensure P writes landed before fragment reads
        asm volatile("s_waitcnt lgkmcnt(0)" ::: "memory");
        __builtin_amdgcn_sched_barrier(0);

        // ---- O += P @ V ----
        const bf16x8 pa0 = *(const bf16x8*)&Ps[w][lc][lg * 8];
        const bf16x8 pa1 = *(const bf16x8*)&Ps[w][lc][32 + lg * 8];
        #pragma unroll
        for (int nt = 0; nt < 4; nt++) {
            const bf16x8 bv0 = *(const bf16x8*)&Vs[16 * nt + lc][lg * 8];
            const bf16x8 bv1 = *(const bf16x8*)&Vs[16 * nt + lc][32 + lg * 8];
            o_acc[nt] = __builtin_amdgcn_mfma_f32_16x16x32_bf16(pa0, bv0, o_acc[nt], 0, 0, 0);
            o_acc[nt] = __builtin_amdgcn_mfma_f32_16x16x32_bf16(pa1, bv1, o_acc[nt], 0, 0, 0);
        }
    }

    // ---- epilogue: normalize and store ----
    #pragma unroll
    for (int r = 0; r < 4; r++) {
        const float inv = 1.0f / lrun[r];
        const int i = i_base + 4 * lg + r;
        float* op = av + ((size_t)i * BSZ + b) * 1024 + n * 64;
        #pragma unroll
        for (int nt = 0; nt < 4; nt++)
            op[16 * nt + lc] = o_acc[nt][r] * inv;
    }
}

// ---------------------------------------------------------------------------
// LayerNorm with residual add (unchanged).
// ---------------------------------------------------------------------------
__global__ __launch_bounds__(256) void ln_kernel(
    const float* __restrict__ x, const float* __restrict__ res,
    const float* __restrict__ scale, const float* __restrict__ bias,
    float* __restrict__ out)
{
    const int row = blockIdx.x;
    const int tid = threadIdx.x;
    const size_t base = (size_t)row * 1024 + tid * 4;
    const float4 xv = *(const float4*)(x + base);
    const float4 rv = *(const float4*)(res + base);
    float v[4] = {xv.x + rv.x, xv.y + rv.y, xv.z + rv.z, xv.w + rv.w};
    float s  = v[0] + v[1] + v[2] + v[3];
    float ss = v[0]*v[0] + v[1]*v[1] + v[2]*v[2] + v[3]*v[3];
    #pragma unroll
    for (int off = 32; off >= 1; off >>= 1) {
        s  += __shfl_down(s, off);
        ss += __shfl_down(ss, off);
    }
    __shared__ float red[8];
    const int lane = tid & 63, wid = tid >> 6;
    if (lane == 0) { red[wid] = s; red[4 + wid] = ss; }
    __syncthreads();
    if (tid == 0) {
        red[0] = red[0] + red[1] + red[2] + red[3];
        red[4] = red[4] + red[5] + red[6] + red[7];
    }
    __syncthreads();
    const float mean = red[0] * (1.0f / 1024.0f);
    const float var  = red[4] * (1.0f / 1024.0f) - mean * mean;
    const float rstd = rsqrtf(var + 1e-5f);
    const float4 sc = *(const float4*)(scale + tid * 4);
    const float4 bi = *(const float4*)(bias + tid * 4);
    float4 o;
    o.x = (v[0] - mean) * rstd * sc.x + bi.x;
    o.y = (v[1] - mean) * rstd * sc.y + bi.y;
    o.z = (v[2] - mean) * rstd * sc.z + bi.z;
    o.w = (v[3] - mean) * rstd * sc.w + bi.w;
    *(float4*)(out + base) = o;
}

// ---------------------------------------------------------------------------
extern "C" void kernel_launch(void* const* d_in, const int* in_sizes, int n_in,
                              void* d_out, int out_size, void* d_ws, size_t ws_size,
                              hipStream_t stream) {
    const float* input_ids = (const float*)d_in[0];
    const float* pos_emb   = (const float*)d_in[1];
    const float* mem       = (const float*)d_in[2];
    const float* c_mem     = (const float*)d_in[3];
    const float* qkv_w     = (const float*)d_in[5];
    const float* r_w       = (const float*)d_in[6];
    const float* o_w       = (const float*)d_in[7];
    const float* r_w_bias  = (const float*)d_in[8];
    const float* r_r_bias  = (const float*)d_in[9];
    const float* ln_a_s    = (const float*)d_in[10];
    const float* ln_a_b    = (const float*)d_in[11];
    const float* ff_w1     = (const float*)d_in[12];
    const float* ff_b1     = (const float*)d_in[13];
    const float* ff_w2     = (const float*)d_in[14];
    const float* ff_b2     = (const float*)d_in[15];
    const float* ln_f_s    = (const float*)d_in[16];
    const float* ln_f_b    = (const float*)d_in[17];

    float* ws = (float*)d_ws;
    float* wh   = ws;                    // 15,728,640 : (KLEN*BSZ, 3072)
    float* rk   = ws + 15728640;         //  2,621,440 : (KLEN, NH*DH)
    float* av   = ws + 18350080;         //  2,097,152 : attn_vec
    float* ao   = ws + 0;                //  2,097,152 : attn_out   (reuses wh)
    float* ares = ws + 2097152;          //  2,097,152 : attn_res   (reuses wh)
    float* h1   = ws + 4194304;          //  8,388,608 : ff hidden  (reuses wh)
    float* h2   = ws + 12582912;         //  2,097,152 : ff out     (reuses wh)

    const dim3 thr(256);

    gemm_f32<0, true><<<dim3(48, 80), thr, 0, stream>>>(
        input_ids, qkv_w, nullptr, wh, 5120, 3072, 1024, mem, 2048, c_mem, 1024);
    gemm_f32<0, false><<<dim3(16, 40), thr, 0, stream>>>(
        pos_emb, r_w, nullptr, rk, 2560, 1024, 1024, nullptr, 0, nullptr, 0);
    attn_mfma<<<dim3(16, 32), thr, 0, stream>>>(wh, rk, r_w_bias, r_r_bias, av);
    gemm_f32<0, false><<<dim3(16, 32), thr, 0, stream>>>(
        av, o_w, nullptr, ao, 2048, 1024, 1024, nullptr, 0, nullptr, 0);
    ln_kernel<<<dim3(2048), thr, 0, stream>>>(ao, input_ids, ln_a_s, ln_a_b, ares);
    gemm_f32<1, false><<<dim3(64, 32), thr, 0, stream>>>(
        ares, ff_w1, ff_b1, h1, 2048, 4096, 1024, nullptr, 0, nullptr, 0);
    gemm_f32<2, false><<<dim3(16, 32), thr, 0, stream>>>(
        h1, ff_w2, ff_b2, h2, 2048, 1024, 4096, nullptr, 0, nullptr, 0);
    ln_kernel<<<dim3(2048), thr, 0, stream>>>(h2, ares, ln_f_s, ln_f_b, (float*)d_out);
}

// Round 3
// 401.864 us; speedup vs baseline: 13.1355x; 3.0704x over previous
//
#include <hip/hip_runtime.h>
#include <hip/hip_bf16.h>

#define QLEN 1024
#define KLEN 2560
#define MTOT 1536   // KLEN - QLEN
#define BSZ 2
#define NH 16
#define DH 64
#define DMODEL 1024
#define DINNER 4096

typedef short bf16x8 __attribute__((ext_vector_type(8)));
typedef float f32x4  __attribute__((ext_vector_type(4)));

__device__ __forceinline__ short f2bf(float f) {
    union { float f; unsigned u; } v; v.f = f;
    unsigned r = v.u + 0x7FFFu + ((v.u >> 16) & 1u);
    return (short)(r >> 16);
}
__device__ __forceinline__ float bf2f(short s) {
    union { unsigned u; float f; } v; v.u = ((unsigned)(unsigned short)s) << 16;
    return v.f;
}
__device__ __forceinline__ unsigned pack2(float a, float b) {
    return (unsigned)(unsigned short)f2bf(a) | ((unsigned)(unsigned short)f2bf(b) << 16);
}

#define GLOAD16(g, l)                                                        \
    __builtin_amdgcn_global_load_lds(                                        \
        (const __attribute__((address_space(1))) unsigned int*)(g),          \
        (__attribute__((address_space(3))) unsigned int*)(l), 16, 0, 0)

// ---------------------------------------------------------------------------
// Elementwise converters
// ---------------------------------------------------------------------------
// cat = [mem | c_mem | input] rows (5120 x 1024) -> bf16
__global__ __launch_bounds__(256) void conv_cat(
    const float* __restrict__ mem, const float* __restrict__ cmem,
    const float* __restrict__ inp, short* __restrict__ out)
{
    const int i = blockIdx.x * 256 + threadIdx.x;   // group of 8 elems
    const int row = i >> 7;
    const int c = (i & 127) * 8;
    const float* src;
    if (row < 2048)      src = mem  + (size_t)row * 1024;
    else if (row < 3072) src = cmem + (size_t)(row - 2048) * 1024;
    else                 src = inp  + (size_t)(row - 3072) * 1024;
    const float4 a = *(const float4*)(src + c);
    const float4 b = *(const float4*)(src + c + 4);
    uint4 o;
    o.x = pack2(a.x, a.y); o.y = pack2(a.z, a.w);
    o.z = pack2(b.x, b.y); o.w = pack2(b.z, b.w);
    *(uint4*)(out + (size_t)i * 8) = o;
}

__global__ __launch_bounds__(256) void conv_flat(
    const float* __restrict__ in, short* __restrict__ out)
{
    const int i = blockIdx.x * 256 + threadIdx.x;
    const float4 a = *(const float4*)(in + (size_t)i * 8);
    const float4 b = *(const float4*)(in + (size_t)i * 8 + 4);
    uint4 o;
    o.x = pack2(a.x, a.y); o.y = pack2(a.z, a.w);
    o.z = pack2(b.x, b.y); o.w = pack2(b.z, b.w);
    *(uint4*)(out + (size_t)i * 8) = o;
}

// in: (K,N) f32 row-major -> out: (N,K) bf16 row-major. Grid (N/64, K/64).
__global__ __launch_bounds__(256) void transpose_conv(
    const float* __restrict__ in, short* __restrict__ out, int K, int N)
{
    __shared__ float ts[64][65];
    const int k0 = blockIdx.y * 64, n0 = blockIdx.x * 64;
    const int tid = threadIdx.x;
    const int r = tid >> 2, cb = (tid & 3) * 16;
    #pragma unroll
    for (int u = 0; u < 16; u += 4) {
        const float4 v = *(const float4*)(in + (size_t)(k0 + r) * N + n0 + cb + u);
        ts[r][cb + u] = v.x; ts[r][cb + u + 1] = v.y;
        ts[r][cb + u + 2] = v.z; ts[r][cb + u + 3] = v.w;
    }
    __syncthreads();
    #pragma unroll
    for (int p = 0; p < 4; p++) {
        const int wr_ = (tid >> 4) + p * 16;   // out row (n)
        const int c   = (tid & 15) * 4;        // out col (k)
        uint2 pk;
        pk.x = pack2(ts[c][wr_], ts[c + 1][wr_]);
        pk.y = pack2(ts[c + 2][wr_], ts[c + 3][wr_]);
        *(uint2*)(out + (size_t)(n0 + wr_) * K + k0 + c) = pk;
    }
}

// ---------------------------------------------------------------------------
// bf16 MFMA GEMM (m97 structure): C(MxN) = A(MxK) @ Bt(NxK)^T
// 128x128 tile, BK=32, 4 waves (2x2 of 64x64), global_load_lds staging.
// EPI: 0 none, 1 bias+relu, 2 bias.  OUTBF: 1 -> write bf16 to Cb else f32 C.
// ---------------------------------------------------------------------------
template <int EPI, int OUTBF>
__global__ __launch_bounds__(256) void gemm_bf16(
    const short* __restrict__ A, const short* __restrict__ Bt,
    const float* __restrict__ bias,
    float* __restrict__ C, short* __restrict__ Cb,
    int M, int N, int K)
{
    __shared__ short As[128 * 32];
    __shared__ short Bs[128 * 32];

    const int tid = threadIdx.x;
    const int w  = tid >> 6;
    const int l  = tid & 63;
    const int lg = l >> 4, lc = l & 15;
    const int wr = w >> 1, wc = w & 1;
    const int bm = blockIdx.y * 128, bn = blockIdx.x * 128;

    // staging: wave w fills LDS chunks 2w, 2w+1 (each 1024B = 16 rows x 32 cols)
    const int srow = 2 * w * 16 + (l >> 2);
    const int scol = (l & 3) * 8;
    const size_t aoff0 = (size_t)(bm + srow) * K + scol;
    const size_t boff0 = (size_t)(bn + srow) * K + scol;
    const size_t rstep = (size_t)16 * K;
    short* lA0 = As + 2 * w * 512;
    short* lA1 = As + (2 * w + 1) * 512;
    short* lB0 = Bs + 2 * w * 512;
    short* lB1 = Bs + (2 * w + 1) * 512;

    f32x4 acc[4][4];
    #pragma unroll
    for (int m = 0; m < 4; m++)
        #pragma unroll
        for (int n = 0; n < 4; n++) acc[m][n] = (f32x4){0.f, 0.f, 0.f, 0.f};

    for (int k0 = 0; k0 < K; k0 += 32) {
        GLOAD16(A + aoff0 + k0, lA0);
        GLOAD16(A + aoff0 + rstep + k0, lA1);
        GLOAD16(Bt + boff0 + k0, lB0);
        GLOAD16(Bt + boff0 + rstep + k0, lB1);
        __syncthreads();   // drains vmcnt: tile resident

        bf16x8 af[4], bfr[4];
        #pragma unroll
        for (int m = 0; m < 4; m++)
            af[m] = *(const bf16x8*)(As + (wr * 64 + m * 16 + lc) * 32 + lg * 8);
        #pragma unroll
        for (int n = 0; n < 4; n++)
            bfr[n] = *(const bf16x8*)(Bs + (wc * 64 + n * 16 + lc) * 32 + lg * 8);
        #pragma unroll
        for (int m = 0; m < 4; m++)
            #pragma unroll
            for (int n = 0; n < 4; n++)
                acc[m][n] = __builtin_amdgcn_mfma_f32_16x16x32_bf16(
                    af[m], bfr[n], acc[m][n], 0, 0, 0);
        __syncthreads();   // all reads done before next stage overwrites
    }

    #pragma unroll
    for (int m = 0; m < 4; m++) {
        #pragma unroll
        for (int n = 0; n < 4; n++) {
            const int col = bn + wc * 64 + n * 16 + lc;
            const float bv = (EPI >= 1) ? bias[col] : 0.0f;
            #pragma unroll
            for (int r = 0; r < 4; r++) {
                const int row = bm + wr * 64 + m * 16 + lg * 4 + r;
                float v = acc[m][n][r] + bv;
                if (EPI == 1) v = fmaxf(v, 0.0f);
                if (OUTBF) Cb[(size_t)row * N + col] = f2bf(v);
                else       C [(size_t)row * N + col] = v;
            }
        }
    }
}

// ---------------------------------------------------------------------------
// MFMA flash attention with fused rel-shift (bf16 inputs/outputs).
// Block: 256 threads = 4 waves; wave w owns 16 query rows. Grid (16, 32).
// ---------------------------------------------------------------------------
__global__ __launch_bounds__(256) void attn_mfma(
    const short* __restrict__ wh,   // (KLEN*BSZ, 3072) bf16
    const short* __restrict__ rk,   // (KLEN, NH*DH) bf16
    const float* __restrict__ rwb,  // (NH, DH)
    const float* __restrict__ rrb,  // (NH, DH)
    short* __restrict__ av)         // (QLEN*BSZ, 1024) bf16
{
    __shared__ __align__(16) short Ks[64][72];
    __shared__ __align__(16) short Vs[64][72];
    __shared__ __align__(16) short Rs[128][72];
    __shared__ __align__(16) short Ps[4][16][72];

    const int i0  = blockIdx.x * 64;
    const int b   = blockIdx.y >> 4;
    const int n   = blockIdx.y & 15;
    const int tid = threadIdx.x;
    const int w   = tid >> 6;
    const int l   = tid & 63;
    const int lg  = l >> 4;
    const int lc  = l & 15;
    const int i_base = i0 + 16 * w;

    bf16x8 aqw[2], aqr[2];
    {
        const int i = i_base + lc;
        const short* qp = wh + ((size_t)(MTOT + i) * BSZ + b) * 3072 + n * 64;
        #pragma unroll
        for (int kc = 0; kc < 2; kc++) {
            const bf16x8 q8 = *(const bf16x8*)(qp + kc * 32 + lg * 8);
            const int d0 = kc * 32 + lg * 8;
            #pragma unroll
            for (int e = 0; e < 8; e++) {
                const float qv = bf2f(q8[e]);
                aqw[kc][e] = f2bf(qv + rwb[n * 64 + d0 + e]);
                aqr[kc][e] = f2bf(qv + rrb[n * 64 + d0 + e]);
            }
        }
    }

    f32x4 o_acc[4];
    #pragma unroll
    for (int nt = 0; nt < 4; nt++) o_acc[nt] = (f32x4){0.f, 0.f, 0.f, 0.f};
    float mrun[4] = {-1e30f, -1e30f, -1e30f, -1e30f};
    float lrun[4] = {0.f, 0.f, 0.f, 0.f};

    const int jend = i0 + 1600;
    for (int j0 = 0; j0 < jend; j0 += 64) {
        __syncthreads();
        {   // stage K (natural) and V (transposed)
            const int row = tid >> 2;
            const int c0  = (tid & 3) * 16;
            const short* kp = wh + ((size_t)(j0 + row) * BSZ + b) * 3072 + 1024 + n * 64 + c0;
            const short* vp = kp + 1024;
            const bf16x8 k0v = *(const bf16x8*)(kp);
            const bf16x8 k1v = *(const bf16x8*)(kp + 8);
            *(bf16x8*)&Ks[row][c0]     = k0v;
            *(bf16x8*)&Ks[row][c0 + 8] = k1v;
            const bf16x8 v0v = *(const bf16x8*)(vp);
            const bf16x8 v1v = *(const bf16x8*)(vp + 8);
            #pragma unroll
            for (int e = 0; e < 8; e++) {
                Vs[c0 + e][row]     = v0v[e];
                Vs[c0 + 8 + e][row] = v1v[e];
            }
        }
        {   // stage R window
            const int row = tid >> 1;
            const int rc0 = (tid & 1) * 32;
            const int m   = j0 - i0 + 960 + row;
            if (m < KLEN) {
                const short* rp = rk + ((size_t)m * NH + n) * 64 + rc0;
                #pragma unroll
                for (int u = 0; u < 4; u++)
                    *(bf16x8*)&Rs[row][rc0 + 8 * u] = *(const bf16x8*)(rp + 8 * u);
            } else {
                #pragma unroll
                for (int u = 0; u < 4; u++)
                    *(bf16x8*)&Rs[row][rc0 + 8 * u] = (bf16x8){0,0,0,0,0,0,0,0};
            }
        }
        __syncthreads();

        // AC = (Q+rwb) @ K^T
        f32x4 sfr[4];
        #pragma unroll
        for (int jt = 0; jt < 4; jt++) {
            const bf16x8 bk0 = *(const bf16x8*)&Ks[16 * jt + lc][lg * 8];
            const bf16x8 bk1 = *(const bf16x8*)&Ks[16 * jt + lc][32 + lg * 8];
            f32x4 acc = (f32x4){0.f, 0.f, 0.f, 0.f};
            acc = __builtin_amdgcn_mfma_f32_16x16x32_bf16(aqw[0], bk0, acc, 0, 0, 0);
            acc = __builtin_amdgcn_mfma_f32_16x16x32_bf16(aqw[1], bk1, acc, 0, 0, 0);
            sfr[jt] = acc;
        }
        // Dr = (Q+rrb) @ R^T (80 shift positions)
        f32x4 dr[5];
        #pragma unroll
        for (int mt = 0; mt < 5; mt++) {
            const int rrow = 16 * mt + lc + 48 - 16 * w;
            const bf16x8 br0 = *(const bf16x8*)&Rs[rrow][lg * 8];
            const bf16x8 br1 = *(const bf16x8*)&Rs[rrow][32 + lg * 8];
            f32x4 acc = (f32x4){0.f, 0.f, 0.f, 0.f};
            acc = __builtin_amdgcn_mfma_f32_16x16x32_bf16(aqr[0], br0, acc, 0, 0, 0);
            acc = __builtin_amdgcn_mfma_f32_16x16x32_bf16(aqr[1], br1, acc, 0, 0, 0);
            dr[mt] = acc;
        }

        // combine (rel-shift diagonal gather) + online softmax
        #pragma unroll
        for (int r = 0; r < 4; r++) {
            const int q   = 4 * lg + r;
            const int o   = lc + 15 - q;
            const int src = (l & 48) | (o & 15);
            float sv[4];
            float mx = -1e30f;
            #pragma unroll
            for (int jt = 0; jt < 4; jt++) {
                const float v0 = __shfl(dr[jt][r], src);
                const float v1 = __shfl(dr[jt + 1][r], src);
                const float bd = (o < 16) ? v0 : v1;
                float s = (sfr[jt][r] + bd) * 0.125f;
                const int j = j0 + 16 * jt + lc;
                if (j > i_base + q + MTOT) s = -1e30f;
                sv[jt] = s;
                mx = fmaxf(mx, s);
            }
            #pragma unroll
            for (int msk = 1; msk <= 8; msk <<= 1)
                mx = fmaxf(mx, __shfl_xor(mx, msk));
            const float mnew = fmaxf(mrun[r], mx);
            const float corr = __expf(mrun[r] - mnew);
            mrun[r] = mnew;
            float ps = 0.f;
            #pragma unroll
            for (int jt = 0; jt < 4; jt++) {
                const float p = __expf(sv[jt] - mnew);
                ps += p;
                Ps[w][q][16 * jt + lc] = f2bf(p);
            }
            #pragma unroll
            for (int msk = 1; msk <= 8; msk <<= 1)
                ps += __shfl_xor(ps, msk);
            lrun[r] = lrun[r] * corr + ps;
            #pragma unroll
            for (int nt = 0; nt < 4; nt++) o_acc[nt][r] *= corr;
        }

        asm volatile("s_waitcnt lgkmcnt(0)" ::: "memory");
        __builtin_amdgcn_sched_barrier(0);

        // O += P @ V
        const bf16x8 pa0 = *(const bf16x8*)&Ps[w][lc][lg * 8];
        const bf16x8 pa1 = *(const bf16x8*)&Ps[w][lc][32 + lg * 8];
        #pragma unroll
        for (int nt = 0; nt < 4; nt++) {
            const bf16x8 bv0 = *(const bf16x8*)&Vs[16 * nt + lc][lg * 8];
            const bf16x8 bv1 = *(const bf16x8*)&Vs[16 * nt + lc][32 + lg * 8];
            o_acc[nt] = __builtin_amdgcn_mfma_f32_16x16x32_bf16(pa0, bv0, o_acc[nt], 0, 0, 0);
            o_acc[nt] = __builtin_amdgcn_mfma_f32_16x16x32_bf16(pa1, bv1, o_acc[nt], 0, 0, 0);
        }
    }

    #pragma unroll
    for (int r = 0; r < 4; r++) {
        const float inv = 1.0f / lrun[r];
        const int i = i_base + 4 * lg + r;
        short* op = av + ((size_t)i * BSZ + b) * 1024 + n * 64;
        #pragma unroll
        for (int nt = 0; nt < 4; nt++)
            op[16 * nt + lc] = f2bf(o_acc[nt][r] * inv);
    }
}

// ---------------------------------------------------------------------------
// LayerNorm with residual add; optional bf16 aux output.
// ---------------------------------------------------------------------------
template <bool WB>
__global__ __launch_bounds__(256) void ln_kernel(
    const float* __restrict__ x, const float* __restrict__ res,
    const float* __restrict__ scale, const float* __restrict__ bias,
    float* __restrict__ out, short* __restrict__ outb)
{
    const int row = blockIdx.x;
    const int tid = threadIdx.x;
    const size_t base = (size_t)row * 1024 + tid * 4;
    const float4 xv = *(const float4*)(x + base);
    const float4 rv = *(const float4*)(res + base);
    float v[4] = {xv.x + rv.x, xv.y + rv.y, xv.z + rv.z, xv.w + rv.w};
    float s  = v[0] + v[1] + v[2] + v[3];
    float ss = v[0]*v[0] + v[1]*v[1] + v[2]*v[2] + v[3]*v[3];
    #pragma unroll
    for (int off = 32; off >= 1; off >>= 1) {
        s  += __shfl_down(s, off);
        ss += __shfl_down(ss, off);
    }
    __shared__ float red[8];
    const int lane = tid & 63, wid = tid >> 6;
    if (lane == 0) { red[wid] = s; red[4 + wid] = ss; }
    __syncthreads();
    if (tid == 0) {
        red[0] = red[0] + red[1] + red[2] + red[3];
        red[4] = red[4] + red[5] + red[6] + red[7];
    }
    __syncthreads();
    const float mean = red[0] * (1.0f / 1024.0f);
    const float var  = red[4] * (1.0f / 1024.0f) - mean * mean;
    const float rstd = rsqrtf(var + 1e-5f);
    const float4 sc = *(const float4*)(scale + tid * 4);
    const float4 bi = *(const float4*)(bias + tid * 4);
    float4 o;
    o.x = (v[0] - mean) * rstd * sc.x + bi.x;
    o.y = (v[1] - mean) * rstd * sc.y + bi.y;
    o.z = (v[2] - mean) * rstd * sc.z + bi.z;
    o.w = (v[3] - mean) * rstd * sc.w + bi.w;
    *(float4*)(out + base) = o;
    if (WB) {
        uint2 pk;
        pk.x = pack2(o.x, o.y);
        pk.y = pack2(o.z, o.w);
        *(uint2*)(outb + base) = pk;
    }
}

// ---------------------------------------------------------------------------
extern "C" void kernel_launch(void* const* d_in, const int* in_sizes, int n_in,
                              void* d_out, int out_size, void* d_ws, size_t ws_size,
                              hipStream_t stream) {
    const float* input_ids = (const float*)d_in[0];
    const float* pos_emb   = (const float*)d_in[1];
    const float* mem       = (const float*)d_in[2];
    const float* c_mem     = (const float*)d_in[3];
    const float* qkv_w     = (const float*)d_in[5];
    const float* r_w       = (const float*)d_in[6];
    const float* o_w       = (const float*)d_in[7];
    const float* r_w_bias  = (const float*)d_in[8];
    const float* r_r_bias  = (const float*)d_in[9];
    const float* ln_a_s    = (const float*)d_in[10];
    const float* ln_a_b    = (const float*)d_in[11];
    const float* ff_w1     = (const float*)d_in[12];
    const float* ff_b1     = (const float*)d_in[13];
    const float* ff_w2     = (const float*)d_in[14];
    const float* ff_b2     = (const float*)d_in[15];
    const float* ln_f_s    = (const float*)d_in[16];
    const float* ln_f_b    = (const float*)d_in[17];

    char* base = (char*)d_ws;
    // static region (lifetimes checked; peak 79.7 MB)
    short* qkv_wt = (short*)(base + 0);          // 3072x1024
    short* r_wt   = (short*)(base + 6291456);    // 1024x1024
    short* o_wt   = (short*)(base + 8388608);    // 1024x1024
    short* ff1t   = (short*)(base + 10485760);   // 4096x1024
    short* ff2t   = (short*)(base + 18874368);   // 1024x4096
    short* catb   = (short*)(base + 27262976);   // 5120x1024
    short* posb   = (short*)(base + 37748736);   // 2560x1024
    short* whb    = (short*)(base + 42991616);   // 5120x3072
    short* rkb    = (short*)(base + 74448896);   // 2560x1024 -> ends 79691776
    // overlays
    short* avb    = (short*)(base + 27262976);   // over catb (dead after GEMM1)
    float* ao     = (float*)(base + 31457280);   // over catb/posb
    float* ares   = (float*)(base + 42991616);   // over whb (dead after attn)
    short* aresb  = (short*)(base + 51380224);
    short* h1b    = (short*)(base + 55574528);   // 2048x4096, ends 72351744
    float* h2     = (float*)(base + 27262976);   // over avb/ao (dead by GEMM5)

    const dim3 thr(256);

    // converts / transposes
    conv_cat<<<dim3(2560), thr, 0, stream>>>(mem, c_mem, input_ids, catb);
    conv_flat<<<dim3(1280), thr, 0, stream>>>(pos_emb, posb);
    transpose_conv<<<dim3(48, 16), thr, 0, stream>>>(qkv_w, qkv_wt, 1024, 3072);
    transpose_conv<<<dim3(16, 16), thr, 0, stream>>>(r_w,   r_wt,   1024, 1024);
    transpose_conv<<<dim3(16, 16), thr, 0, stream>>>(o_w,   o_wt,   1024, 1024);
    transpose_conv<<<dim3(64, 16), thr, 0, stream>>>(ff_w1, ff1t,   1024, 4096);
    transpose_conv<<<dim3(16, 64), thr, 0, stream>>>(ff_w2, ff2t,   4096, 1024);

    // 1) w_heads (bf16 out)
    gemm_bf16<0, 1><<<dim3(24, 40), thr, 0, stream>>>(
        catb, qkv_wt, nullptr, nullptr, whb, 5120, 3072, 1024);
    // 2) r_k (bf16 out)
    gemm_bf16<0, 1><<<dim3(8, 20), thr, 0, stream>>>(
        posb, r_wt, nullptr, nullptr, rkb, 2560, 1024, 1024);
    // 3) attention -> avb (bf16)
    attn_mfma<<<dim3(16, 32), thr, 0, stream>>>(whb, rkb, r_w_bias, r_r_bias, avb);
    // 4) attn_out (f32)
    gemm_bf16<0, 0><<<dim3(8, 16), thr, 0, stream>>>(
        avb, o_wt, nullptr, ao, nullptr, 2048, 1024, 1024);
    // 5) attn_res = LN(input + attn_out), f32 + bf16
    ln_kernel<true><<<dim3(2048), thr, 0, stream>>>(ao, input_ids, ln_a_s, ln_a_b, ares, aresb);
    // 6) h1 = relu(ares @ ff_w1 + b1) (bf16 out)
    gemm_bf16<1, 1><<<dim3(32, 16), thr, 0, stream>>>(
        aresb, ff1t, ff_b1, nullptr, h1b, 2048, 4096, 1024);
    // 7) h2 = h1 @ ff_w2 + b2 (f32 out)
    gemm_bf16<2, 0><<<dim3(8, 16), thr, 0, stream>>>(
        h1b, ff2t, ff_b2, h2, nullptr, 2048, 1024, 4096);
    // 8) out = LN(ares + h2)
    ln_kernel<false><<<dim3(2048), thr, 0, stream>>>(h2, ares, ln_f_s, ln_f_b, (float*)d_out, nullptr);
}